// Round 2
// baseline (14230.580 us; speedup 1.0000x reference)
//
#include <hip/hip_runtime.h>
#include <hip/hip_cooperative_groups.h>

namespace cg = cooperative_groups;

#define NT 499    // T-1 sequential steps
#define NB 64     // batch (= wave size, lane = b)
#define NN 512    // region width
#define ND 100    // input dim
#define NO 10     // output dim
#define NWG 128   // workgroups; each owns NCOL output columns of all 3 regions
#define NCOL 4

// workspace layout (floats) — unchanged
#define XT_SZ   (NT * ND * NB)     // XT[t][d][b] = X[t+1][b][d]
#define RBUF_SZ (2 * NN * NB)      // double-buffered rT[buf][n][b]
#define XT_OFF  0
#define RM_OFF  (XT_OFF + XT_SZ)
#define RP_OFF  (RM_OFF + RBUF_SZ)
#define RS_OFF  (RP_OFF + RBUF_SZ)
#define FLAG_OFF (RS_OFF + RBUF_SZ)   // flags @ stride 16 words + 1 gen word

// Agent-scope coherent accesses for the cross-WG r state: compile to sc-bit
// global_load/store served at the coherence point. NO buffer_wbl2/buffer_inv
// anywhere -> weights/X stay hot in K$/L1/L2 across all 499 steps.
__device__ __forceinline__ float ld_cg(const float* p) {
  return __hip_atomic_load(p, __ATOMIC_RELAXED, __HIP_MEMORY_SCOPE_AGENT);
}
__device__ __forceinline__ void st_cg(float* p, float v) {
  __hip_atomic_store(p, v, __ATOMIC_RELAXED, __HIP_MEMORY_SCOPE_AGENT);
}

// Transpose X[t+1][b][d] -> XT[t][d][b] so the main loop's lane=b loads coalesce.
__global__ void xpose_kernel(const float* __restrict__ X, float* __restrict__ XT) {
  __shared__ float tile[NB * ND];
  const int t = blockIdx.x;
  const float* src = X + (size_t)(t + 1) * NB * ND;
  for (int i = threadIdx.x; i < NB * ND; i += blockDim.x) tile[i] = src[i];
  __syncthreads();
  float* dst = XT + (size_t)t * ND * NB;
  for (int i = threadIdx.x; i < NB * ND; i += blockDim.x) {
    const int d = i >> 6, b = i & 63;
    dst[i] = tile[b * ND + d];
  }
}

// Persistent cooperative kernel: 128 WGs x 512 threads (8 waves, 2/SIMD).
// WG g owns columns n0=4g..4g+3 of all three regions; waves k-split 8x64.
__global__ void __launch_bounds__(512)
rnn_kernel(const float* __restrict__ XT,
           float* __restrict__ r_m1, float* __restrict__ r_pmd, float* __restrict__ r_s1,
           const float* __restrict__ W_rec_m1, const float* __restrict__ W_rec_pmd,
           const float* __restrict__ W_rec_s1,
           const float* __restrict__ b_m1, const float* __restrict__ b_pmd,
           const float* __restrict__ b_s1,
           const float* __restrict__ W_pmd_m1, const float* __restrict__ W_s1_m1,
           const float* __restrict__ W_m1_pmd, const float* __restrict__ W_in_pmd,
           const float* __restrict__ W_in_s1, const float* __restrict__ W_out,
           float* __restrict__ out,
           unsigned* __restrict__ flags, unsigned* __restrict__ gen)
{
  const int g    = blockIdx.x;
  const int wave = __builtin_amdgcn_readfirstlane((int)threadIdx.x >> 6);
  const int lane = (int)threadIdx.x & 63;
  const int n0 = NCOL * g;
  const int k0 = __builtin_amdgcn_readfirstlane(wave * 64);
  const int d0 = __builtin_amdgcn_readfirstlane(wave * 13);
  const int dlen = (ND - d0 < 13) ? (ND - d0) : 13;   // waves0-6:13, wave7:9
  const bool has_out = (n0 < NO);                      // g < 3

  __shared__ float red[8][16][64];

  // ws is poisoned before every launch: zero r slot 0 and barrier words.
  for (int i = g * (int)blockDim.x + (int)threadIdx.x; i < NN * NB;
       i += (int)(gridDim.x * blockDim.x)) {
    r_m1[i] = 0.f; r_pmd[i] = 0.f; r_s1[i] = 0.f;
  }
  if (threadIdx.x == 0) flags[g * 16] = 0u;
  if (g == 0 && threadIdx.x == 1) *gen = 0u;

  // wave-uniform weight bases (scalarized): row c at +c*NN, col k at +k.
  const float* wrmB = W_rec_m1  + (size_t)n0 * NN + k0;
  const float* wmpB = W_m1_pmd  + (size_t)n0 * NN + k0;
  const float* wpmB = W_pmd_m1  + (size_t)n0 * NN + k0;
  const float* wrpB = W_rec_pmd + (size_t)n0 * NN + k0;
  const float* wsmB = W_s1_m1   + (size_t)n0 * NN + k0;
  const float* wrsB = W_rec_s1  + (size_t)n0 * NN + k0;
  const float* wipB = W_in_pmd  + (size_t)n0 * ND + d0;
  const float* wisB = W_in_s1   + (size_t)n0 * ND + d0;
  // W_out row pointers, CLAMPED per column (R1 bug: g=2 read rows 10,11 OOB
  // -> page fault -> container death). Invalid columns read row 0 harmlessly;
  // their results are never stored (colA < NO / o < NO guards).
  const float* woC[NCOL];
  #pragma unroll
  for (int c = 0; c < NCOL; ++c) {
    const int row = (n0 + c < NO) ? (n0 + c) : 0;
    woC[c] = W_out + (size_t)row * NN + k0;
  }

  // per-wave persistent x-state (lane = b):
  //   wave<4 : taskA = m1 col n0+wave, taskB = s1 col n0+wave
  //   wave>=4: taskA = pmd col n0+wave-4, taskB = out row n0+wave-4
  const int colA = (wave < 4) ? (n0 + wave) : (n0 + wave - 4);
  const float bA = (wave < 4) ? b_m1[colA] : b_pmd[colA];
  const float bB = (wave < 4) ? b_s1[colA] : 0.f;
  float xA = 0.f, xB = 0.f;

  // one-time heavyweight sync to order init (flags/r zeroing) grid-wide
  cg::this_grid().sync();

  for (int ti = 0; ti < NT; ++ti) {
    const int cur = ti & 1, nxt = cur ^ 1;
    const float* rm = r_m1 + cur * NN * NB + k0 * NB + lane;
    const float* rp = r_pmd + cur * NN * NB + k0 * NB + lane;
    const float* rs = r_s1 + cur * NN * NB + k0 * NB + lane;
    float am[NCOL], ap[NCOL], as_[NCOL], ao[NCOL];
    #pragma unroll
    for (int c = 0; c < NCOL; ++c) { am[c] = 0.f; ap[c] = 0.f; as_[c] = 0.f; ao[c] = 0.f; }

    // source Xt -> pmd, s1
    {
      const float* xt = XT + (size_t)ti * ND * NB + d0 * NB + lane;
      for (int d = 0; d < dlen; ++d) {
        const float v = xt[d * NB];
        #pragma unroll
        for (int c = 0; c < NCOL; ++c) {
          ap[c]  = fmaf(v, wipB[c * ND + d], ap[c]);
          as_[c] = fmaf(v, wisB[c * ND + d], as_[c]);
        }
      }
    }

    // source r_m1 -> m1(rec), pmd(m1->pmd) [+ out rows for g<3]
    if (has_out) {
      #pragma unroll 32
      for (int k = 0; k < 64; ++k) {
        const float v = ld_cg(rm + k * NB);
        #pragma unroll
        for (int c = 0; c < NCOL; ++c) {
          am[c] = fmaf(v, wrmB[c * NN + k], am[c]);
          ap[c] = fmaf(v, wmpB[c * NN + k], ap[c]);
          ao[c] = fmaf(v, woC[c][k], ao[c]);
        }
      }
    } else {
      #pragma unroll 32
      for (int k = 0; k < 64; ++k) {
        const float v = ld_cg(rm + k * NB);
        #pragma unroll
        for (int c = 0; c < NCOL; ++c) {
          am[c] = fmaf(v, wrmB[c * NN + k], am[c]);
          ap[c] = fmaf(v, wmpB[c * NN + k], ap[c]);
        }
      }
    }
    // source r_pmd -> m1(pmd->m1), pmd(rec)
    #pragma unroll 32
    for (int k = 0; k < 64; ++k) {
      const float v = ld_cg(rp + k * NB);
      #pragma unroll
      for (int c = 0; c < NCOL; ++c) {
        am[c] = fmaf(v, wpmB[c * NN + k], am[c]);
        ap[c] = fmaf(v, wrpB[c * NN + k], ap[c]);
      }
    }
    // source r_s1 -> m1(s1->m1), s1(rec)
    #pragma unroll 32
    for (int k = 0; k < 64; ++k) {
      const float v = ld_cg(rs + k * NB);
      #pragma unroll
      for (int c = 0; c < NCOL; ++c) {
        am[c]  = fmaf(v, wsmB[c * NN + k], am[c]);
        as_[c] = fmaf(v, wrsB[c * NN + k], as_[c]);
      }
    }

    #pragma unroll
    for (int c = 0; c < NCOL; ++c) {
      red[wave][c][lane]      = am[c];
      red[wave][4 + c][lane]  = ap[c];
      red[wave][8 + c][lane]  = as_[c];
      red[wave][12 + c][lane] = ao[c];
    }
    __syncthreads();

    // publish parallelized across all 8 waves: 2 reduce tasks each
    {
      const int jA = wave, jB = wave + 8;
      float sA = red[0][jA][lane], sB = red[0][jB][lane];
      #pragma unroll
      for (int w = 1; w < 8; ++w) { sA += red[w][jA][lane]; sB += red[w][jB][lane]; }
      if (wave < 4) {
        xA = 0.9f * xA + 0.1f * (sA + bA);          // m1 col colA
        xB = 0.9f * xB + 0.1f * (sB + bB);          // s1 col colA
        st_cg(r_m1 + nxt * NN * NB + colA * NB + lane, tanhf(xA));
        st_cg(r_s1 + nxt * NN * NB + colA * NB + lane, tanhf(xB));
      } else {
        xA = 0.9f * xA + 0.1f * (sA + bA);          // pmd col colA
        st_cg(r_pmd + nxt * NN * NB + colA * NB + lane, tanhf(xA));
        if (has_out && colA < NO && ti > 0) {
          out[(size_t)(ti - 1) * (NB * NO) + lane * NO + colA] = sB;
        }
      }
    }

    // ---- grid barrier: no fences. st_cg (sc-coherent) stores drain at the
    // vmcnt(0) __syncthreads emits before s_barrier; flag store follows. ----
    __syncthreads();
    const unsigned tgt = (unsigned)ti + 1u;
    if (threadIdx.x == 0) {
      __hip_atomic_store(&flags[g * 16], tgt, __ATOMIC_RELAXED, __HIP_MEMORY_SCOPE_AGENT);
    }
    if (g == 0) {
      if (threadIdx.x < NWG) {
        while (__hip_atomic_load(&flags[threadIdx.x * 16], __ATOMIC_RELAXED,
                                 __HIP_MEMORY_SCOPE_AGENT) < tgt)
          __builtin_amdgcn_s_sleep(1);
      }
      __syncthreads();
      if (threadIdx.x == 0) {
        __hip_atomic_store(gen, tgt, __ATOMIC_RELAXED, __HIP_MEMORY_SCOPE_AGENT);
      }
      __syncthreads();
    } else {
      if (threadIdx.x == 0) {
        while (__hip_atomic_load(gen, __ATOMIC_RELAXED,
                                 __HIP_MEMORY_SCOPE_AGENT) < tgt)
          __builtin_amdgcn_s_sleep(1);
      }
      __syncthreads();
    }
  }

  // epilogue: out[NT-1] from final r_m1 (visible via the loop's final barrier)
  if (has_out) {
    const float* rm = r_m1 + (NT & 1) * NN * NB + k0 * NB + lane;
    float ao2[NCOL];
    #pragma unroll
    for (int c = 0; c < NCOL; ++c) ao2[c] = 0.f;
    #pragma unroll 32
    for (int k = 0; k < 64; ++k) {
      const float v = ld_cg(rm + k * NB);
      #pragma unroll
      for (int c = 0; c < NCOL; ++c) ao2[c] = fmaf(v, woC[c][k], ao2[c]);
    }
    #pragma unroll
    for (int c = 0; c < NCOL; ++c) red[wave][12 + c][lane] = ao2[c];
    __syncthreads();
    if (wave >= 4) {
      const int c = wave - 4, o = n0 + c;
      float t = red[0][12 + c][lane];
      #pragma unroll
      for (int w = 1; w < 8; ++w) t += red[w][12 + c][lane];
      if (o < NO) out[(size_t)(NT - 1) * (NB * NO) + lane * NO + o] = t;
    }
  }
}

extern "C" void kernel_launch(void* const* d_in, const int* in_sizes, int n_in,
                              void* d_out, int out_size, void* d_ws, size_t ws_size,
                              hipStream_t stream) {
  (void)in_sizes; (void)n_in; (void)out_size; (void)ws_size;
  const float* X         = (const float*)d_in[0];
  const float* W_rec_m1  = (const float*)d_in[1];
  const float* W_rec_pmd = (const float*)d_in[2];
  const float* W_rec_s1  = (const float*)d_in[3];
  const float* b_m1      = (const float*)d_in[4];
  const float* b_pmd     = (const float*)d_in[5];
  const float* b_s1      = (const float*)d_in[6];
  const float* W_pmd_m1  = (const float*)d_in[7];
  const float* W_s1_m1   = (const float*)d_in[8];
  const float* W_m1_pmd  = (const float*)d_in[9];
  const float* W_in_pmd  = (const float*)d_in[10];
  const float* W_in_s1   = (const float*)d_in[11];
  const float* W_out     = (const float*)d_in[12];
  float* out = (float*)d_out;

  float* wsf = (float*)d_ws;
  const float* XT = wsf + XT_OFF;
  float* XTw   = wsf + XT_OFF;
  float* r_m1  = wsf + RM_OFF;
  float* r_pmd = wsf + RP_OFF;
  float* r_s1  = wsf + RS_OFF;
  unsigned* flags = (unsigned*)(wsf + FLAG_OFF);
  unsigned* gen   = flags + 256 * 16;

  xpose_kernel<<<NT, 256, 0, stream>>>(X, XTw);

  void* args[19];
  args[0]  = (void*)&XT;
  args[1]  = (void*)&r_m1;  args[2]  = (void*)&r_pmd; args[3]  = (void*)&r_s1;
  args[4]  = (void*)&W_rec_m1; args[5] = (void*)&W_rec_pmd; args[6] = (void*)&W_rec_s1;
  args[7]  = (void*)&b_m1;  args[8]  = (void*)&b_pmd; args[9]  = (void*)&b_s1;
  args[10] = (void*)&W_pmd_m1; args[11] = (void*)&W_s1_m1; args[12] = (void*)&W_m1_pmd;
  args[13] = (void*)&W_in_pmd; args[14] = (void*)&W_in_s1; args[15] = (void*)&W_out;
  args[16] = (void*)&out;
  args[17] = (void*)&flags;
  args[18] = (void*)&gen;
  hipLaunchCooperativeKernel((const void*)rnn_kernel, dim3(NWG), dim3(512), args, 0, stream);
}

// Round 3
// 6600.745 us; speedup vs baseline: 2.1559x; 2.1559x over previous
//
#include <hip/hip_runtime.h>
#include <hip/hip_cooperative_groups.h>

namespace cg = cooperative_groups;

#define NT 499    // T-1 sequential steps
#define NB 64     // batch (= wave size, lane = b)
#define NN 512    // region width
#define ND 100    // input dim
#define NO 10     // output dim

// workspace layout (floats)
#define XT_SZ   (NT * ND * NB)     // XT[t][d][b] = X[t+1][b][d]
#define RBUF_SZ (2 * NN * NB)      // double-buffered rT[buf][n][b]
#define XT_OFF  0
#define RM_OFF  (XT_OFF + XT_SZ)
#define RP_OFF  (RM_OFF + RBUF_SZ)
#define RS_OFF  (RP_OFF + RBUF_SZ)
#define FLAG_OFF (RS_OFF + RBUF_SZ)   // 256 flags @ stride 16 words + 1 gen word

// sc write-through store: publishes r to the coherence point directly, so NO
// release fence (buffer_wbl2 drain) is needed anywhere. Proven correct in R2:
// __syncthreads' vmcnt(0) drains these before the flag store issues.
__device__ __forceinline__ void st_cg(float* p, float v) {
  __hip_atomic_store(p, v, __ATOMIC_RELAXED, __HIP_MEMORY_SCOPE_AGENT);
}

// Transpose X[t+1][b][d] -> XT[t][d][b] so the main loop's lane=b loads coalesce.
__global__ void xpose_kernel(const float* __restrict__ X, float* __restrict__ XT) {
  __shared__ float tile[NB * ND];
  const int t = blockIdx.x;
  const float* src = X + (size_t)(t + 1) * NB * ND;
  for (int i = threadIdx.x; i < NB * ND; i += blockDim.x) tile[i] = src[i];
  __syncthreads();
  float* dst = XT + (size_t)t * ND * NB;
  for (int i = threadIdx.x; i < NB * ND; i += blockDim.x) {
    const int d = i >> 6, b = i & 63;
    dst[i] = tile[b * ND + d];
  }
}

// Persistent cooperative kernel: 256 WGs x 512 threads (R0 geometry — proven
// best codegen: plain loads fold offsets, weights scalarize to s_load/K$).
// Deltas vs R0: (1) r publishes are sc write-through -> release threadfence
// (wbl2 storm) REMOVED; (2) acquire side kept as acquire-ONLY fence
// (buffer_inv, no wbl2); (3) X-part of step t+1 computed between flag store
// and gen poll to hide barrier propagation latency.
__global__ void __launch_bounds__(512)
rnn_kernel(const float* __restrict__ XT,
           float* __restrict__ r_m1, float* __restrict__ r_pmd, float* __restrict__ r_s1,
           const float* __restrict__ W_rec_m1, const float* __restrict__ W_rec_pmd,
           const float* __restrict__ W_rec_s1,
           const float* __restrict__ b_m1, const float* __restrict__ b_pmd,
           const float* __restrict__ b_s1,
           const float* __restrict__ W_pmd_m1, const float* __restrict__ W_s1_m1,
           const float* __restrict__ W_m1_pmd, const float* __restrict__ W_in_pmd,
           const float* __restrict__ W_in_s1, const float* __restrict__ W_out,
           float* __restrict__ out,
           unsigned* __restrict__ flags, unsigned* __restrict__ gen)
{
  const int g    = blockIdx.x;
  const int wave = __builtin_amdgcn_readfirstlane((int)threadIdx.x >> 6);
  const int lane = (int)threadIdx.x & 63;
  const int n0 = 2 * g, n1 = 2 * g + 1;
  const int k0 = __builtin_amdgcn_readfirstlane(wave * 64);
  const int d0 = __builtin_amdgcn_readfirstlane(wave * 13);
  const int dlen = (ND - d0 < 13) ? (ND - d0) : 13;   // waves0-6:13, wave7:9
  const bool has_out = (g < NO);

  __shared__ float red[8][7][64];

  // ws is poisoned before every launch: zero r slot 0 and barrier words.
  for (int i = g * (int)blockDim.x + (int)threadIdx.x; i < NN * NB;
       i += (int)(gridDim.x * blockDim.x)) {
    r_m1[i] = 0.f; r_pmd[i] = 0.f; r_s1[i] = 0.f;
  }
  if (threadIdx.x == 0) flags[g * 16] = 0u;
  if (g == 0 && threadIdx.x == 1) *gen = 0u;

  // wave-uniform weight row pointers -> scalar loads (K$-resident)
  const float bm0 = b_m1[n0],  bm1 = b_m1[n1];
  const float bp0 = b_pmd[n0], bp1 = b_pmd[n1];
  const float bs0 = b_s1[n0],  bs1 = b_s1[n1];
  const float* wrm0 = W_rec_m1 + (size_t)n0 * NN + k0;
  const float* wrm1 = W_rec_m1 + (size_t)n1 * NN + k0;
  const float* wmp0 = W_m1_pmd + (size_t)n0 * NN + k0;
  const float* wmp1 = W_m1_pmd + (size_t)n1 * NN + k0;
  const float* wpm0 = W_pmd_m1 + (size_t)n0 * NN + k0;
  const float* wpm1 = W_pmd_m1 + (size_t)n1 * NN + k0;
  const float* wrp0 = W_rec_pmd + (size_t)n0 * NN + k0;
  const float* wrp1 = W_rec_pmd + (size_t)n1 * NN + k0;
  const float* wsm0 = W_s1_m1 + (size_t)n0 * NN + k0;
  const float* wsm1 = W_s1_m1 + (size_t)n1 * NN + k0;
  const float* wrs0 = W_rec_s1 + (size_t)n0 * NN + k0;
  const float* wrs1 = W_rec_s1 + (size_t)n1 * NN + k0;
  const float* wip0 = W_in_pmd + (size_t)n0 * ND + d0;
  const float* wip1 = W_in_pmd + (size_t)n1 * ND + d0;
  const float* wis0 = W_in_s1 + (size_t)n0 * ND + d0;
  const float* wis1 = W_in_s1 + (size_t)n1 * ND + d0;
  const float* wo   = W_out + (size_t)(has_out ? g : 0) * NN + k0;

  // persistent x-state (wave0, lane = b)
  float xm0 = 0.f, xm1 = 0.f, xp0 = 0.f, xp1 = 0.f, xs0 = 0.f, xs1 = 0.f;

  // X-part accumulators for the upcoming step (computed during barrier wait)
  float apX0 = 0.f, apX1 = 0.f, asX0 = 0.f, asX1 = 0.f;
  {
    const float* xt = XT + d0 * NB + lane;   // ti = 0
    for (int d = 0; d < dlen; ++d) {
      const float v = xt[d * NB];
      apX0 = fmaf(v, wip0[d], apX0);
      apX1 = fmaf(v, wip1[d], apX1);
      asX0 = fmaf(v, wis0[d], asX0);
      asX1 = fmaf(v, wis1[d], asX1);
    }
  }

  // one-time heavyweight sync to order init (flags/r zeroing) grid-wide
  cg::this_grid().sync();

  for (int ti = 0; ti < NT; ++ti) {
    const int cur = ti & 1, nxt = cur ^ 1;
    const float* rm = r_m1 + cur * NN * NB + k0 * NB + lane;
    const float* rp = r_pmd + cur * NN * NB + k0 * NB + lane;
    const float* rs = r_s1 + cur * NN * NB + k0 * NB + lane;
    // start from the X-part precomputed during the previous barrier wait
    float am0 = 0.f, am1 = 0.f, ao = 0.f;
    float ap0 = apX0, ap1 = apX1, as0 = asX0, as1 = asX1;

    // source r_m1 -> m1(rec), pmd(m1->pmd)
    #pragma unroll 16
    for (int k = 0; k < 64; ++k) {
      const float v = rm[k * NB];
      am0 = fmaf(v, wrm0[k], am0);
      am1 = fmaf(v, wrm1[k], am1);
      ap0 = fmaf(v, wmp0[k], ap0);
      ap1 = fmaf(v, wmp1[k], ap1);
    }
    if (has_out) {
      #pragma unroll 16
      for (int k = 0; k < 64; ++k) ao = fmaf(rm[k * NB], wo[k], ao);
    }
    // source r_pmd -> m1(pmd->m1), pmd(rec)
    #pragma unroll 16
    for (int k = 0; k < 64; ++k) {
      const float v = rp[k * NB];
      am0 = fmaf(v, wpm0[k], am0);
      am1 = fmaf(v, wpm1[k], am1);
      ap0 = fmaf(v, wrp0[k], ap0);
      ap1 = fmaf(v, wrp1[k], ap1);
    }
    // source r_s1 -> m1(s1->m1), s1(rec)
    #pragma unroll 16
    for (int k = 0; k < 64; ++k) {
      const float v = rs[k * NB];
      am0 = fmaf(v, wsm0[k], am0);
      am1 = fmaf(v, wsm1[k], am1);
      as0 = fmaf(v, wrs0[k], as0);
      as1 = fmaf(v, wrs1[k], as1);
    }

    red[wave][0][lane] = am0; red[wave][1][lane] = am1;
    red[wave][2][lane] = ap0; red[wave][3][lane] = ap1;
    red[wave][4][lane] = as0; red[wave][5][lane] = as1;
    red[wave][6][lane] = ao;
    __syncthreads();

    if (wave == 0) {
      float s[7];
      #pragma unroll
      for (int j = 0; j < 7; ++j) {
        float t = red[0][j][lane];
        #pragma unroll
        for (int w = 1; w < 8; ++w) t += red[w][j][lane];
        s[j] = t;
      }
      xm0 = 0.9f * xm0 + 0.1f * (s[0] + bm0);
      xm1 = 0.9f * xm1 + 0.1f * (s[1] + bm1);
      xp0 = 0.9f * xp0 + 0.1f * (s[2] + bp0);
      xp1 = 0.9f * xp1 + 0.1f * (s[3] + bp1);
      xs0 = 0.9f * xs0 + 0.1f * (s[4] + bs0);
      xs1 = 0.9f * xs1 + 0.1f * (s[5] + bs1);
      float* rmw = r_m1 + nxt * NN * NB;
      float* rpw = r_pmd + nxt * NN * NB;
      float* rsw = r_s1 + nxt * NN * NB;
      // sc write-through publish: data reaches the coherence point directly,
      // no buffer_wbl2 release needed (R2-proven protocol)
      st_cg(&rmw[n0 * NB + lane], tanhf(xm0));
      st_cg(&rmw[n1 * NB + lane], tanhf(xm1));
      st_cg(&rpw[n0 * NB + lane], tanhf(xp0));
      st_cg(&rpw[n1 * NB + lane], tanhf(xp1));
      st_cg(&rsw[n0 * NB + lane], tanhf(xs0));
      st_cg(&rsw[n1 * NB + lane], tanhf(xs1));
      if (has_out && ti > 0) {
        out[(size_t)(ti - 1) * (NB * NO) + lane * NO + g] = s[6];
      }
    }

    // ---- grid barrier: flag store ordered behind r publishes by the
    // vmcnt(0) __syncthreads emits; NO release fence anywhere. ----
    __syncthreads();
    const unsigned tgt = (unsigned)ti + 1u;
    if (threadIdx.x == 0) {
      __hip_atomic_store(&flags[g * 16], tgt, __ATOMIC_RELAXED, __HIP_MEMORY_SCOPE_AGENT);
    }

    // overlap: X-part of step ti+1 (depends only on static XT/W_in) computed
    // while the barrier propagates through the coherence point
    apX0 = 0.f; apX1 = 0.f; asX0 = 0.f; asX1 = 0.f;
    if (ti + 1 < NT) {
      const float* xt = XT + (size_t)(ti + 1) * ND * NB + d0 * NB + lane;
      for (int d = 0; d < dlen; ++d) {
        const float v = xt[d * NB];
        apX0 = fmaf(v, wip0[d], apX0);
        apX1 = fmaf(v, wip1[d], apX1);
        asX0 = fmaf(v, wis0[d], asX0);
        asX1 = fmaf(v, wis1[d], asX1);
      }
    }

    if (g == 0) {
      if (threadIdx.x < 256) {
        while (__hip_atomic_load(&flags[threadIdx.x * 16], __ATOMIC_RELAXED,
                                 __HIP_MEMORY_SCOPE_AGENT) < tgt)
          __builtin_amdgcn_s_sleep(1);
      }
      __syncthreads();
      if (threadIdx.x == 0) {
        // acquire-only: invalidate stale L1/L2 r lines for this CU/XCD
        __builtin_amdgcn_fence(__ATOMIC_ACQUIRE, "agent");
        __hip_atomic_store(gen, tgt, __ATOMIC_RELAXED, __HIP_MEMORY_SCOPE_AGENT);
      }
      __syncthreads();
    } else {
      if (threadIdx.x == 0) {
        while (__hip_atomic_load(gen, __ATOMIC_RELAXED,
                                 __HIP_MEMORY_SCOPE_AGENT) < tgt)
          __builtin_amdgcn_s_sleep(1);
        __builtin_amdgcn_fence(__ATOMIC_ACQUIRE, "agent");   // acquire-only
      }
      __syncthreads();
    }
  }

  // epilogue: out[NT-1] from final r_m1 (fresh via the loop's final acquire)
  if (has_out) {
    const float* rm = r_m1 + (NT & 1) * NN * NB + k0 * NB + lane;
    float ao = 0.f;
    #pragma unroll 16
    for (int k = 0; k < 64; ++k) ao = fmaf(rm[k * NB], wo[k], ao);
    red[wave][6][lane] = ao;
    __syncthreads();
    if (wave == 0) {
      float t = red[0][6][lane];
      #pragma unroll
      for (int w = 1; w < 8; ++w) t += red[w][6][lane];
      out[(size_t)(NT - 1) * (NB * NO) + lane * NO + g] = t;
    }
  }
}

extern "C" void kernel_launch(void* const* d_in, const int* in_sizes, int n_in,
                              void* d_out, int out_size, void* d_ws, size_t ws_size,
                              hipStream_t stream) {
  (void)in_sizes; (void)n_in; (void)out_size; (void)ws_size;
  const float* X         = (const float*)d_in[0];
  const float* W_rec_m1  = (const float*)d_in[1];
  const float* W_rec_pmd = (const float*)d_in[2];
  const float* W_rec_s1  = (const float*)d_in[3];
  const float* b_m1      = (const float*)d_in[4];
  const float* b_pmd     = (const float*)d_in[5];
  const float* b_s1      = (const float*)d_in[6];
  const float* W_pmd_m1  = (const float*)d_in[7];
  const float* W_s1_m1   = (const float*)d_in[8];
  const float* W_m1_pmd  = (const float*)d_in[9];
  const float* W_in_pmd  = (const float*)d_in[10];
  const float* W_in_s1   = (const float*)d_in[11];
  const float* W_out     = (const float*)d_in[12];
  float* out = (float*)d_out;

  float* wsf = (float*)d_ws;
  const float* XT = wsf + XT_OFF;
  float* XTw   = wsf + XT_OFF;
  float* r_m1  = wsf + RM_OFF;
  float* r_pmd = wsf + RP_OFF;
  float* r_s1  = wsf + RS_OFF;
  unsigned* flags = (unsigned*)(wsf + FLAG_OFF);
  unsigned* gen   = flags + 256 * 16;

  xpose_kernel<<<NT, 256, 0, stream>>>(X, XTw);

  void* args[19];
  args[0]  = (void*)&XT;
  args[1]  = (void*)&r_m1;  args[2]  = (void*)&r_pmd; args[3]  = (void*)&r_s1;
  args[4]  = (void*)&W_rec_m1; args[5] = (void*)&W_rec_pmd; args[6] = (void*)&W_rec_s1;
  args[7]  = (void*)&b_m1;  args[8]  = (void*)&b_pmd; args[9]  = (void*)&b_s1;
  args[10] = (void*)&W_pmd_m1; args[11] = (void*)&W_s1_m1; args[12] = (void*)&W_m1_pmd;
  args[13] = (void*)&W_in_pmd; args[14] = (void*)&W_in_s1; args[15] = (void*)&W_out;
  args[16] = (void*)&out;
  args[17] = (void*)&flags;
  args[18] = (void*)&gen;
  hipLaunchCooperativeKernel((const void*)rnn_kernel, dim3(256), dim3(512), args, 0, stream);
}

// Round 4
// 6085.830 us; speedup vs baseline: 2.3383x; 1.0846x over previous
//
#include <hip/hip_runtime.h>
#include <hip/hip_cooperative_groups.h>

namespace cg = cooperative_groups;

#define NT 499    // T-1 sequential steps
#define NB 64     // batch (= wave size, lane = b)
#define NN 512    // region width
#define ND 100    // input dim
#define NO 10     // output dim
#define NWAVE 16  // waves per WG (1024 threads) -> 4 waves/SIMD for latency hiding
#define KW 32     // k-slice width per wave (16*32 = 512)

// workspace layout (floats)
#define XT_SZ   (NT * ND * NB)     // XT[t][d][b] = X[t+1][b][d]
#define RBUF_SZ (2 * NN * NB)      // double-buffered rT[buf][n][b]
#define XT_OFF  0
#define RM_OFF  (XT_OFF + XT_SZ)
#define RP_OFF  (RM_OFF + RBUF_SZ)
#define RS_OFF  (RP_OFF + RBUF_SZ)
#define FLAG_OFF (RS_OFF + RBUF_SZ)   // 256 flags @ stride 16 words + 1 gen word

// sc write-through store: publishes r to the coherence point directly, so NO
// release fence (buffer_wbl2 drain) is needed anywhere (R2/R3-proven:
// __syncthreads' vmcnt(0) drains these before the flag store issues).
__device__ __forceinline__ void st_cg(float* p, float v) {
  __hip_atomic_store(p, v, __ATOMIC_RELAXED, __HIP_MEMORY_SCOPE_AGENT);
}

// Transpose X[t+1][b][d] -> XT[t][d][b] so the main loop's lane=b loads coalesce.
__global__ void xpose_kernel(const float* __restrict__ X, float* __restrict__ XT) {
  __shared__ float tile[NB * ND];
  const int t = blockIdx.x;
  const float* src = X + (size_t)(t + 1) * NB * ND;
  for (int i = threadIdx.x; i < NB * ND; i += blockDim.x) tile[i] = src[i];
  __syncthreads();
  float* dst = XT + (size_t)t * ND * NB;
  for (int i = threadIdx.x; i < NB * ND; i += blockDim.x) {
    const int d = i >> 6, b = i & 63;
    dst[i] = tile[b * ND + d];
  }
}

// Persistent cooperative kernel: 256 WGs x 1024 threads (16 waves = 4/SIMD).
// WG g owns columns n0=2g, n0+1; waves k-split 16x32. Publish distributed
// over waves 0-6 (one reduce target each, one float of x-state per wave).
// Barrier protocol unchanged from R3 (fence-free publish, acquire-only).
__global__ void __launch_bounds__(1024)
rnn_kernel(const float* __restrict__ XT,
           float* __restrict__ r_m1, float* __restrict__ r_pmd, float* __restrict__ r_s1,
           const float* __restrict__ W_rec_m1, const float* __restrict__ W_rec_pmd,
           const float* __restrict__ W_rec_s1,
           const float* __restrict__ b_m1, const float* __restrict__ b_pmd,
           const float* __restrict__ b_s1,
           const float* __restrict__ W_pmd_m1, const float* __restrict__ W_s1_m1,
           const float* __restrict__ W_m1_pmd, const float* __restrict__ W_in_pmd,
           const float* __restrict__ W_in_s1, const float* __restrict__ W_out,
           float* __restrict__ out,
           unsigned* __restrict__ flags, unsigned* __restrict__ gen)
{
  const int g    = blockIdx.x;
  const int wave = __builtin_amdgcn_readfirstlane((int)threadIdx.x >> 6);
  const int lane = (int)threadIdx.x & 63;
  const int n0 = 2 * g, n1 = 2 * g + 1;
  const int k0 = __builtin_amdgcn_readfirstlane(wave * KW);
  const int d0 = __builtin_amdgcn_readfirstlane(wave * 7);   // 16*7=112 covers ND=100
  int dlen = ND - d0; dlen = dlen < 0 ? 0 : (dlen > 7 ? 7 : dlen);
  const bool has_out = (g < NO);

  __shared__ float red[NWAVE][7][64];   // 28 KB

  // ws is poisoned before every launch: zero r slot 0 and barrier words.
  for (int i = g * (int)blockDim.x + (int)threadIdx.x; i < NN * NB;
       i += (int)(gridDim.x * blockDim.x)) {
    r_m1[i] = 0.f; r_pmd[i] = 0.f; r_s1[i] = 0.f;
  }
  if (threadIdx.x == 0) flags[g * 16] = 0u;
  if (g == 0 && threadIdx.x == 1) *gen = 0u;

  // wave-uniform weight row pointers -> scalar loads (K$-resident)
  const float* wrm0 = W_rec_m1 + (size_t)n0 * NN + k0;
  const float* wrm1 = W_rec_m1 + (size_t)n1 * NN + k0;
  const float* wmp0 = W_m1_pmd + (size_t)n0 * NN + k0;
  const float* wmp1 = W_m1_pmd + (size_t)n1 * NN + k0;
  const float* wpm0 = W_pmd_m1 + (size_t)n0 * NN + k0;
  const float* wpm1 = W_pmd_m1 + (size_t)n1 * NN + k0;
  const float* wrp0 = W_rec_pmd + (size_t)n0 * NN + k0;
  const float* wrp1 = W_rec_pmd + (size_t)n1 * NN + k0;
  const float* wsm0 = W_s1_m1 + (size_t)n0 * NN + k0;
  const float* wsm1 = W_s1_m1 + (size_t)n1 * NN + k0;
  const float* wrs0 = W_rec_s1 + (size_t)n0 * NN + k0;
  const float* wrs1 = W_rec_s1 + (size_t)n1 * NN + k0;
  const float* wip0 = W_in_pmd + (size_t)n0 * ND + d0;
  const float* wip1 = W_in_pmd + (size_t)n1 * ND + d0;
  const float* wis0 = W_in_s1 + (size_t)n0 * ND + d0;
  const float* wis1 = W_in_s1 + (size_t)n1 * ND + d0;
  const float* wo   = W_out + (size_t)(has_out ? g : 0) * NN + k0;

  // publish role: wave j<7 owns reduce target j
  //   j=0: m1/n0  j=1: m1/n1  j=2: pmd/n0  j=3: pmd/n1  j=4: s1/n0  j=5: s1/n1  j=6: out
  float* pubBase = nullptr; float bP = 0.f;
  if (wave == 0)      { pubBase = r_m1  + n0 * NB; bP = b_m1[n0]; }
  else if (wave == 1) { pubBase = r_m1  + n1 * NB; bP = b_m1[n1]; }
  else if (wave == 2) { pubBase = r_pmd + n0 * NB; bP = b_pmd[n0]; }
  else if (wave == 3) { pubBase = r_pmd + n1 * NB; bP = b_pmd[n1]; }
  else if (wave == 4) { pubBase = r_s1  + n0 * NB; bP = b_s1[n0]; }
  else if (wave == 5) { pubBase = r_s1  + n1 * NB; bP = b_s1[n1]; }
  float xP = 0.f;   // per-wave persistent x-state (lane = b)

  // X-part accumulators for the upcoming step (computed during barrier wait)
  float apX0 = 0.f, apX1 = 0.f, asX0 = 0.f, asX1 = 0.f;
  {
    const float* xt = XT + d0 * NB + lane;   // ti = 0
    for (int d = 0; d < dlen; ++d) {
      const float v = xt[d * NB];
      apX0 = fmaf(v, wip0[d], apX0);
      apX1 = fmaf(v, wip1[d], apX1);
      asX0 = fmaf(v, wis0[d], asX0);
      asX1 = fmaf(v, wis1[d], asX1);
    }
  }

  // one-time heavyweight sync to order init (flags/r zeroing) grid-wide
  cg::this_grid().sync();

  for (int ti = 0; ti < NT; ++ti) {
    const int cur = ti & 1, nxt = cur ^ 1;
    const float* rm = r_m1 + cur * NN * NB + k0 * NB + lane;
    const float* rp = r_pmd + cur * NN * NB + k0 * NB + lane;
    const float* rs = r_s1 + cur * NN * NB + k0 * NB + lane;
    float am0 = 0.f, am1 = 0.f, ao = 0.f;
    float ap0 = apX0, ap1 = apX1, as0 = asX0, as1 = asX1;

    // source r_m1 -> m1(rec), pmd(m1->pmd)
    #pragma unroll
    for (int k = 0; k < KW; ++k) {
      const float v = rm[k * NB];
      am0 = fmaf(v, wrm0[k], am0);
      am1 = fmaf(v, wrm1[k], am1);
      ap0 = fmaf(v, wmp0[k], ap0);
      ap1 = fmaf(v, wmp1[k], ap1);
    }
    if (has_out) {
      #pragma unroll
      for (int k = 0; k < KW; ++k) ao = fmaf(rm[k * NB], wo[k], ao);
    }
    // source r_pmd -> m1(pmd->m1), pmd(rec)
    #pragma unroll
    for (int k = 0; k < KW; ++k) {
      const float v = rp[k * NB];
      am0 = fmaf(v, wpm0[k], am0);
      am1 = fmaf(v, wpm1[k], am1);
      ap0 = fmaf(v, wrp0[k], ap0);
      ap1 = fmaf(v, wrp1[k], ap1);
    }
    // source r_s1 -> m1(s1->m1), s1(rec)
    #pragma unroll
    for (int k = 0; k < KW; ++k) {
      const float v = rs[k * NB];
      am0 = fmaf(v, wsm0[k], am0);
      am1 = fmaf(v, wsm1[k], am1);
      as0 = fmaf(v, wrs0[k], as0);
      as1 = fmaf(v, wrs1[k], as1);
    }

    red[wave][0][lane] = am0; red[wave][1][lane] = am1;
    red[wave][2][lane] = ap0; red[wave][3][lane] = ap1;
    red[wave][4][lane] = as0; red[wave][5][lane] = as1;
    red[wave][6][lane] = ao;
    __syncthreads();

    // publish: distributed — wave j reduces target j, applies leaky+tanh,
    // sc write-through publish (no release fence needed)
    if (wave < 7) {
      float s = red[0][wave][lane];
      #pragma unroll
      for (int w = 1; w < NWAVE; ++w) s += red[w][wave][lane];
      if (wave < 6) {
        xP = 0.9f * xP + 0.1f * (s + bP);
        st_cg(pubBase + nxt * NN * NB + lane, tanhf(xP));
      } else if (has_out && ti > 0) {
        out[(size_t)(ti - 1) * (NB * NO) + lane * NO + g] = s;
      }
    }

    // ---- grid barrier: flag store ordered behind r publishes by the
    // vmcnt(0) __syncthreads emits; NO release fence anywhere. ----
    __syncthreads();
    const unsigned tgt = (unsigned)ti + 1u;
    if (threadIdx.x == 0) {
      __hip_atomic_store(&flags[g * 16], tgt, __ATOMIC_RELAXED, __HIP_MEMORY_SCOPE_AGENT);
    }

    // overlap: X-part of step ti+1 (static data) during barrier propagation
    apX0 = 0.f; apX1 = 0.f; asX0 = 0.f; asX1 = 0.f;
    if (ti + 1 < NT) {
      const float* xt = XT + (size_t)(ti + 1) * ND * NB + d0 * NB + lane;
      for (int d = 0; d < dlen; ++d) {
        const float v = xt[d * NB];
        apX0 = fmaf(v, wip0[d], apX0);
        apX1 = fmaf(v, wip1[d], apX1);
        asX0 = fmaf(v, wis0[d], asX0);
        asX1 = fmaf(v, wis1[d], asX1);
      }
    }

    if (g == 0) {
      if (threadIdx.x < 256) {
        while (__hip_atomic_load(&flags[threadIdx.x * 16], __ATOMIC_RELAXED,
                                 __HIP_MEMORY_SCOPE_AGENT) < tgt)
          __builtin_amdgcn_s_sleep(1);
      }
      __syncthreads();
      if (threadIdx.x == 0) {
        __builtin_amdgcn_fence(__ATOMIC_ACQUIRE, "agent");   // acquire-only
        __hip_atomic_store(gen, tgt, __ATOMIC_RELAXED, __HIP_MEMORY_SCOPE_AGENT);
      }
      __syncthreads();
    } else {
      if (threadIdx.x == 0) {
        while (__hip_atomic_load(gen, __ATOMIC_RELAXED,
                                 __HIP_MEMORY_SCOPE_AGENT) < tgt)
          __builtin_amdgcn_s_sleep(1);
        __builtin_amdgcn_fence(__ATOMIC_ACQUIRE, "agent");   // acquire-only
      }
      __syncthreads();
    }
  }

  // epilogue: out[NT-1] from final r_m1 (fresh via the loop's final acquire)
  if (has_out) {
    const float* rm = r_m1 + (NT & 1) * NN * NB + k0 * NB + lane;
    float ao = 0.f;
    #pragma unroll
    for (int k = 0; k < KW; ++k) ao = fmaf(rm[k * NB], wo[k], ao);
    red[wave][6][lane] = ao;
    __syncthreads();
    if (wave == 6) {
      float t = red[0][6][lane];
      #pragma unroll
      for (int w = 1; w < NWAVE; ++w) t += red[w][6][lane];
      out[(size_t)(NT - 1) * (NB * NO) + lane * NO + g] = t;
    }
  }
}

extern "C" void kernel_launch(void* const* d_in, const int* in_sizes, int n_in,
                              void* d_out, int out_size, void* d_ws, size_t ws_size,
                              hipStream_t stream) {
  (void)in_sizes; (void)n_in; (void)out_size; (void)ws_size;
  const float* X         = (const float*)d_in[0];
  const float* W_rec_m1  = (const float*)d_in[1];
  const float* W_rec_pmd = (const float*)d_in[2];
  const float* W_rec_s1  = (const float*)d_in[3];
  const float* b_m1      = (const float*)d_in[4];
  const float* b_pmd     = (const float*)d_in[5];
  const float* b_s1      = (const float*)d_in[6];
  const float* W_pmd_m1  = (const float*)d_in[7];
  const float* W_s1_m1   = (const float*)d_in[8];
  const float* W_m1_pmd  = (const float*)d_in[9];
  const float* W_in_pmd  = (const float*)d_in[10];
  const float* W_in_s1   = (const float*)d_in[11];
  const float* W_out     = (const float*)d_in[12];
  float* out = (float*)d_out;

  float* wsf = (float*)d_ws;
  const float* XT = wsf + XT_OFF;
  float* XTw   = wsf + XT_OFF;
  float* r_m1  = wsf + RM_OFF;
  float* r_pmd = wsf + RP_OFF;
  float* r_s1  = wsf + RS_OFF;
  unsigned* flags = (unsigned*)(wsf + FLAG_OFF);
  unsigned* gen   = flags + 256 * 16;

  xpose_kernel<<<NT, 256, 0, stream>>>(X, XTw);

  void* args[19];
  args[0]  = (void*)&XT;
  args[1]  = (void*)&r_m1;  args[2]  = (void*)&r_pmd; args[3]  = (void*)&r_s1;
  args[4]  = (void*)&W_rec_m1; args[5] = (void*)&W_rec_pmd; args[6] = (void*)&W_rec_s1;
  args[7]  = (void*)&b_m1;  args[8]  = (void*)&b_pmd; args[9]  = (void*)&b_s1;
  args[10] = (void*)&W_pmd_m1; args[11] = (void*)&W_s1_m1; args[12] = (void*)&W_m1_pmd;
  args[13] = (void*)&W_in_pmd; args[14] = (void*)&W_in_s1; args[15] = (void*)&W_out;
  args[16] = (void*)&out;
  args[17] = (void*)&flags;
  args[18] = (void*)&gen;
  hipLaunchCooperativeKernel((const void*)rnn_kernel, dim3(256), dim3(1024), args, 0, stream);
}